// Round 5
// baseline (213.129 us; speedup 1.0000x reference)
//
#include <hip/hip_runtime.h>

#define N_NODES 4096
#define B_PTS   4096
#define SUPPORT_FACTOR 2.5f
#define EPSILON 1e-5f

// ---------------------------------------------------------------------------
// Kernel 1: per-node nearest-neighbor distance (no atomics).
// One block per node i; float4 loads (2 nodes each); wave+LDS min reduce.
// ---------------------------------------------------------------------------
__global__ __launch_bounds__(256) void nearest_kernel(
        const float* __restrict__ nodes, float* __restrict__ mind) {
    const int i = blockIdx.x;
    const float xi = nodes[2 * i];
    const float yi = nodes[2 * i + 1];

    const float4* nodes4 = (const float4*)nodes;  // 2 nodes per float4
    float mind2 = 3.4e38f;
    for (int k = threadIdx.x; k < N_NODES / 2; k += 256) {
        float4 v = nodes4[k];
        float dx0 = xi - v.x, dy0 = yi - v.y;
        float dx1 = xi - v.z, dy1 = yi - v.w;
        float d20 = dx0 * dx0 + dy0 * dy0;
        float d21 = dx1 * dx1 + dy1 * dy1;
        if (2 * k != i)     mind2 = fminf(mind2, d20);
        if (2 * k + 1 != i) mind2 = fminf(mind2, d21);
    }
    #pragma unroll
    for (int off = 32; off > 0; off >>= 1)
        mind2 = fminf(mind2, __shfl_down(mind2, off, 64));

    __shared__ float sw[4];
    const int wave = threadIdx.x >> 6;
    if ((threadIdx.x & 63) == 0) sw[wave] = mind2;
    __syncthreads();
    if (threadIdx.x == 0) {
        float m = fminf(fminf(sw[0], sw[1]), fminf(sw[2], sw[3]));
        mind[i] = sqrtf(m);
    }
}

// ---------------------------------------------------------------------------
// Cubic spline weight (zero outside q > 1)
// ---------------------------------------------------------------------------
__device__ __forceinline__ float cubic_w(float q) {
    if (q <= 0.5f) return 2.0f / 3.0f + q * q * (4.0f * q - 4.0f);
    if (q <= 1.0f) return 4.0f / 3.0f + q * (-4.0f + q * (4.0f - (4.0f / 3.0f) * q));
    return 0.0f;
}

// ---------------------------------------------------------------------------
// Kernel 2 (fused): one block per query point b.
//  Phase 0: block-reduce mind[] -> dilation (redundant per block, L2-resident)
//  Phase 1: nodes read once (2x float4/thread/iter, coalesced); only w cached
//           in 16 VGPRs; moment matrix accumulate
//  Phase 2: thread 0 analytic adjugate inverse (negated deriv rows)
//  Phase 3: SPARSITY FAST PATH — support radius ~0.04 covers ~49/4096 nodes,
//           so for most (query, 256-node chunk) pairs every lane has w==0:
//           wave-uniform __any skips the node reload + 11 FMA/node and stores
//           zero float4s straight away. Slow path (rare) reloads nodes from L1.
// ---------------------------------------------------------------------------
__global__ __launch_bounds__(256, 6) void rkpm_kernel(
        const float* __restrict__ x, const float* __restrict__ nodes,
        const float* __restrict__ mind, float* __restrict__ out) {
    __shared__ float sred[4][6];
    __shared__ float sbc[10];   // [0]=inv_dil, [1..9]=inverse rows (phi, -dx, -dy)

    const int b = blockIdx.x;
    const int tid = threadIdx.x;
    const int wave = tid >> 6;
    const int lane = tid & 63;

    // ---- phase 0: dilation from mind[] ----
    const float4* m4 = (const float4*)mind;
    float s = 0.f;
    #pragma unroll
    for (int k = 0; k < 4; ++k) {
        float4 v = m4[k * 256 + tid];
        s += (v.x + v.y) + (v.z + v.w);
    }
    #pragma unroll
    for (int off = 32; off > 0; off >>= 1)
        s += __shfl_down(s, off, 64);
    if (lane == 0) sred[wave][0] = s;
    __syncthreads();
    if (tid == 0) {
        float dil = (sred[0][0] + sred[1][0] + sred[2][0] + sred[3][0]) *
                    (SUPPORT_FACTOR / (float)N_NODES);
        sbc[0] = 1.0f / dil;
    }
    __syncthreads();
    const float inv_dil = sbc[0];

    const float2 xq = ((const float2*)x)[b];
    const float xb = xq.x, yb = xq.y;

    // ---- phase 1: moment matrix; cache only w ----
    const float4* nodes4 = (const float4*)nodes;   // 2 nodes per float4
    float wr[16];
    float m00 = 0.f, m01 = 0.f, m02 = 0.f, m11 = 0.f, m12 = 0.f, m22 = 0.f;
    #pragma unroll
    for (int kk = 0; kk < 4; ++kk) {
        float4 va = nodes4[kk * 512 + 2 * tid];      // nodes 4t, 4t+1 (of chunk)
        float4 vb = nodes4[kk * 512 + 2 * tid + 1];  // nodes 4t+2, 4t+3
        #pragma unroll
        for (int c = 0; c < 4; ++c) {
            float nx = (c == 0) ? va.x : (c == 1) ? va.z : (c == 2) ? vb.x : vb.z;
            float ny = (c == 0) ? va.y : (c == 1) ? va.w : (c == 2) ? vb.y : vb.w;
            float dx = xb - nx;
            float dy = yb - ny;
            float dist = sqrtf(dx * dx + dy * dy + 1e-10f);
            float w = cubic_w(dist * inv_dil);
            wr[kk * 4 + c] = w;
            m00 += w;
            m01 += w * dx;
            m02 += w * dy;
            m11 += w * dx * dx;
            m12 += w * dx * dy;
            m22 += w * dy * dy;
        }
    }
    #pragma unroll
    for (int off = 32; off > 0; off >>= 1) {
        m00 += __shfl_down(m00, off, 64);
        m01 += __shfl_down(m01, off, 64);
        m02 += __shfl_down(m02, off, 64);
        m11 += __shfl_down(m11, off, 64);
        m12 += __shfl_down(m12, off, 64);
        m22 += __shfl_down(m22, off, 64);
    }
    if (lane == 0) {
        sred[wave][0] = m00; sred[wave][1] = m01; sred[wave][2] = m02;
        sred[wave][3] = m11; sred[wave][4] = m12; sred[wave][5] = m22;
    }
    __syncthreads();

    // ---- phase 2: analytic symmetric 3x3 inverse ----
    if (tid == 0) {
        float a  = sred[0][0] + sred[1][0] + sred[2][0] + sred[3][0] + EPSILON;
        float bb = sred[0][1] + sred[1][1] + sred[2][1] + sred[3][1];
        float c  = sred[0][2] + sred[1][2] + sred[2][2] + sred[3][2];
        float d  = sred[0][3] + sred[1][3] + sred[2][3] + sred[3][3] + EPSILON;
        float e  = sred[0][4] + sred[1][4] + sred[2][4] + sred[3][4];
        float f  = sred[0][5] + sred[1][5] + sred[2][5] + sred[3][5] + EPSILON;
        float c00 = d * f - e * e;
        float c01 = c * e - bb * f;
        float c02 = bb * e - c * d;
        float det = a * c00 + bb * c01 + c * c02;
        float idet = 1.0f / det;
        float i00 = c00 * idet;
        float i01 = c01 * idet;
        float i02 = c02 * idet;
        float i11 = (a * f - c * c) * idet;
        float i12 = (bb * c - a * e) * idet;
        float i22 = (a * d - bb * bb) * idet;
        sbc[1] = i00;  sbc[2] = i01;  sbc[3] = i02;   // phi row
        sbc[4] = -i01; sbc[5] = -i11; sbc[6] = -i12;  // phi_x row (negated)
        sbc[7] = -i02; sbc[8] = -i12; sbc[9] = -i22;  // phi_y row (negated)
    }
    __syncthreads();

    const float i00 = sbc[1], i01 = sbc[2], i02 = sbc[3];
    const float n01 = sbc[4], n11 = sbc[5], n12 = sbc[6];
    const float n02 = sbc[7], n12b = sbc[8], n22 = sbc[9];

    const size_t BN = (size_t)B_PTS * N_NODES;
    float4* __restrict__ out_phi = (float4*)(out + (size_t)b * N_NODES);
    float4* __restrict__ out_px  = (float4*)(out + BN + (size_t)b * N_NODES);
    float4* __restrict__ out_py  = (float4*)(out + 2 * BN + (size_t)b * N_NODES);

    // ---- phase 3: wave-uniform zero-skip + float4 stores ----
    #pragma unroll
    for (int kk = 0; kk < 4; ++kk) {
        const int idx = kk * 256 + tid;
        const bool nz = (wr[kk * 4 + 0] != 0.f) | (wr[kk * 4 + 1] != 0.f) |
                        (wr[kk * 4 + 2] != 0.f) | (wr[kk * 4 + 3] != 0.f);
        if (__any(nz)) {
            // slow path (rare): reload nodes (L1-resident), full evaluation
            float4 va = nodes4[kk * 512 + 2 * tid];
            float4 vb = nodes4[kk * 512 + 2 * tid + 1];
            float4 ph, px, py;
            #pragma unroll
            for (int c = 0; c < 4; ++c) {
                float nx = (c == 0) ? va.x : (c == 1) ? va.z : (c == 2) ? vb.x : vb.z;
                float ny = (c == 0) ? va.y : (c == 1) ? va.w : (c == 2) ? vb.y : vb.w;
                float dx = xb - nx;
                float dy = yb - ny;
                float w = wr[kk * 4 + c];
                float vph = w * (i00 + i01 * dx + i02 * dy);
                float vpx = w * (n01 + n11 * dx + n12 * dy);
                float vpy = w * (n02 + n12b * dx + n22 * dy);
                if (c == 0)      { ph.x = vph; px.x = vpx; py.x = vpy; }
                else if (c == 1) { ph.y = vph; px.y = vpx; py.y = vpy; }
                else if (c == 2) { ph.z = vph; px.z = vpx; py.z = vpy; }
                else             { ph.w = vph; px.w = vpx; py.w = vpy; }
            }
            out_phi[idx] = ph;
            out_px[idx]  = px;
            out_py[idx]  = py;
        } else {
            // fast path: whole wave's chunk is outside support -> zeros
            const float4 z = make_float4(0.f, 0.f, 0.f, 0.f);
            out_phi[idx] = z;
            out_px[idx]  = z;
            out_py[idx]  = z;
        }
    }
}

extern "C" void kernel_launch(void* const* d_in, const int* in_sizes, int n_in,
                              void* d_out, int out_size, void* d_ws, size_t ws_size,
                              hipStream_t stream) {
    const float* x     = (const float*)d_in[0];   // [4096, 2]
    const float* nodes = (const float*)d_in[1];   // [4096, 2]
    float* out  = (float*)d_out;                  // 3 * 4096 * 4096 floats
    float* mind = (float*)d_ws;                   // [4096] nearest distances

    nearest_kernel<<<N_NODES, 256, 0, stream>>>(nodes, mind);
    rkpm_kernel<<<B_PTS, 256, 0, stream>>>(x, nodes, mind, out);
}

// Round 6
// 209.108 us; speedup vs baseline: 1.0192x; 1.0192x over previous
//
#include <hip/hip_runtime.h>

#define N_NODES 4096
#define B_PTS   4096
#define SUPPORT_FACTOR 2.5f
#define EPSILON 1e-5f

// ---------------------------------------------------------------------------
// Kernel 1: per-node nearest-neighbor distance (no atomics).
// One block per node i; float4 loads (2 nodes each); wave+LDS min reduce.
// ---------------------------------------------------------------------------
__global__ __launch_bounds__(256) void nearest_kernel(
        const float* __restrict__ nodes, float* __restrict__ mind) {
    const int i = blockIdx.x;
    const float xi = nodes[2 * i];
    const float yi = nodes[2 * i + 1];

    const float4* nodes4 = (const float4*)nodes;  // 2 nodes per float4
    float mind2 = 3.4e38f;
    for (int k = threadIdx.x; k < N_NODES / 2; k += 256) {
        float4 v = nodes4[k];
        float dx0 = xi - v.x, dy0 = yi - v.y;
        float dx1 = xi - v.z, dy1 = yi - v.w;
        float d20 = dx0 * dx0 + dy0 * dy0;
        float d21 = dx1 * dx1 + dy1 * dy1;
        if (2 * k != i)     mind2 = fminf(mind2, d20);
        if (2 * k + 1 != i) mind2 = fminf(mind2, d21);
    }
    #pragma unroll
    for (int off = 32; off > 0; off >>= 1)
        mind2 = fminf(mind2, __shfl_down(mind2, off, 64));

    __shared__ float sw[4];
    const int wave = threadIdx.x >> 6;
    if ((threadIdx.x & 63) == 0) sw[wave] = mind2;
    __syncthreads();
    if (threadIdx.x == 0) {
        float m = fminf(fminf(sw[0], sw[1]), fminf(sw[2], sw[3]));
        mind[i] = sqrtf(m);
    }
}

// ---------------------------------------------------------------------------
// Cubic spline weight (zero outside q > 1)
// ---------------------------------------------------------------------------
__device__ __forceinline__ float cubic_w(float q) {
    if (q <= 0.5f) return 2.0f / 3.0f + q * q * (4.0f * q - 4.0f);
    if (q <= 1.0f) return 4.0f / 3.0f + q * (-4.0f + q * (4.0f - (4.0f / 3.0f) * q));
    return 0.0f;
}

// ---------------------------------------------------------------------------
// Kernel 2 (fused): one block per query point b.  [R4 winner — reverted from
// R5's sparsity fast path, which regressed: epilogue VALU is fully hidden
// under the mandatory 192 MiB store traffic, so the branch only added cost.]
//  Phase 0: block-reduce mind[] -> dilation (redundant per block, L2-resident)
//  Phase 1: nodes read once (2x float4/thread/iter, coalesced, L2-resident);
//           w/dx/dy cached in 48 VGPRs; moment matrix accumulate
//  Phase 2: thread 0 analytic adjugate inverse (negated deriv rows)
//  Phase 3: pure-register epilogue, float4 coalesced stores
// ---------------------------------------------------------------------------
__global__ __launch_bounds__(256, 4) void rkpm_kernel(
        const float* __restrict__ x, const float* __restrict__ nodes,
        const float* __restrict__ mind, float* __restrict__ out) {
    __shared__ float sred[4][6];
    __shared__ float sbc[10];   // [0]=inv_dil, [1..9]=inverse rows (phi, -dx, -dy)

    const int b = blockIdx.x;
    const int tid = threadIdx.x;
    const int wave = tid >> 6;
    const int lane = tid & 63;

    // ---- phase 0: dilation from mind[] ----
    const float4* m4 = (const float4*)mind;
    float s = 0.f;
    #pragma unroll
    for (int k = 0; k < 4; ++k) {
        float4 v = m4[k * 256 + tid];
        s += (v.x + v.y) + (v.z + v.w);
    }
    #pragma unroll
    for (int off = 32; off > 0; off >>= 1)
        s += __shfl_down(s, off, 64);
    if (lane == 0) sred[wave][0] = s;
    __syncthreads();
    if (tid == 0) {
        float dil = (sred[0][0] + sred[1][0] + sred[2][0] + sred[3][0]) *
                    (SUPPORT_FACTOR / (float)N_NODES);
        sbc[0] = 1.0f / dil;
    }
    __syncthreads();
    const float inv_dil = sbc[0];

    const float2 xq = ((const float2*)x)[b];
    const float xb = xq.x, yb = xq.y;

    // ---- phase 1: moment matrix; cache w, dx, dy ----
    const float4* nodes4 = (const float4*)nodes;   // 2 nodes per float4
    float wr[16], dxr[16], dyr[16];
    float m00 = 0.f, m01 = 0.f, m02 = 0.f, m11 = 0.f, m12 = 0.f, m22 = 0.f;
    #pragma unroll
    for (int kk = 0; kk < 4; ++kk) {
        float4 va = nodes4[kk * 512 + 2 * tid];      // nodes 4t, 4t+1 (of chunk)
        float4 vb = nodes4[kk * 512 + 2 * tid + 1];  // nodes 4t+2, 4t+3
        #pragma unroll
        for (int c = 0; c < 4; ++c) {
            float nx = (c == 0) ? va.x : (c == 1) ? va.z : (c == 2) ? vb.x : vb.z;
            float ny = (c == 0) ? va.y : (c == 1) ? va.w : (c == 2) ? vb.y : vb.w;
            float dx = xb - nx;
            float dy = yb - ny;
            float dist = sqrtf(dx * dx + dy * dy + 1e-10f);
            float w = cubic_w(dist * inv_dil);
            const int r = kk * 4 + c;
            wr[r] = w; dxr[r] = dx; dyr[r] = dy;
            m00 += w;
            m01 += w * dx;
            m02 += w * dy;
            m11 += w * dx * dx;
            m12 += w * dx * dy;
            m22 += w * dy * dy;
        }
    }
    #pragma unroll
    for (int off = 32; off > 0; off >>= 1) {
        m00 += __shfl_down(m00, off, 64);
        m01 += __shfl_down(m01, off, 64);
        m02 += __shfl_down(m02, off, 64);
        m11 += __shfl_down(m11, off, 64);
        m12 += __shfl_down(m12, off, 64);
        m22 += __shfl_down(m22, off, 64);
    }
    if (lane == 0) {
        sred[wave][0] = m00; sred[wave][1] = m01; sred[wave][2] = m02;
        sred[wave][3] = m11; sred[wave][4] = m12; sred[wave][5] = m22;
    }
    __syncthreads();

    // ---- phase 2: analytic symmetric 3x3 inverse ----
    if (tid == 0) {
        float a  = sred[0][0] + sred[1][0] + sred[2][0] + sred[3][0] + EPSILON;
        float bb = sred[0][1] + sred[1][1] + sred[2][1] + sred[3][1];
        float c  = sred[0][2] + sred[1][2] + sred[2][2] + sred[3][2];
        float d  = sred[0][3] + sred[1][3] + sred[2][3] + sred[3][3] + EPSILON;
        float e  = sred[0][4] + sred[1][4] + sred[2][4] + sred[3][4];
        float f  = sred[0][5] + sred[1][5] + sred[2][5] + sred[3][5] + EPSILON;
        float c00 = d * f - e * e;
        float c01 = c * e - bb * f;
        float c02 = bb * e - c * d;
        float det = a * c00 + bb * c01 + c * c02;
        float idet = 1.0f / det;
        float i00 = c00 * idet;
        float i01 = c01 * idet;
        float i02 = c02 * idet;
        float i11 = (a * f - c * c) * idet;
        float i12 = (bb * c - a * e) * idet;
        float i22 = (a * d - bb * bb) * idet;
        sbc[1] = i00;  sbc[2] = i01;  sbc[3] = i02;   // phi row
        sbc[4] = -i01; sbc[5] = -i11; sbc[6] = -i12;  // phi_x row (negated)
        sbc[7] = -i02; sbc[8] = -i12; sbc[9] = -i22;  // phi_y row (negated)
    }
    __syncthreads();

    const float i00 = sbc[1], i01 = sbc[2], i02 = sbc[3];
    const float n01 = sbc[4], n11 = sbc[5], n12 = sbc[6];
    const float n02 = sbc[7], n12b = sbc[8], n22 = sbc[9];

    const size_t BN = (size_t)B_PTS * N_NODES;
    float4* __restrict__ out_phi = (float4*)(out + (size_t)b * N_NODES);
    float4* __restrict__ out_px  = (float4*)(out + BN + (size_t)b * N_NODES);
    float4* __restrict__ out_py  = (float4*)(out + 2 * BN + (size_t)b * N_NODES);

    // ---- phase 3: pure-register epilogue, float4 stores ----
    #pragma unroll
    for (int kk = 0; kk < 4; ++kk) {
        float4 ph, px, py;
        #pragma unroll
        for (int c = 0; c < 4; ++c) {
            const int r = kk * 4 + c;
            float w = wr[r], dx = dxr[r], dy = dyr[r];
            float vph = w * (i00 + i01 * dx + i02 * dy);
            float vpx = w * (n01 + n11 * dx + n12 * dy);
            float vpy = w * (n02 + n12b * dx + n22 * dy);
            if (c == 0)      { ph.x = vph; px.x = vpx; py.x = vpy; }
            else if (c == 1) { ph.y = vph; px.y = vpx; py.y = vpy; }
            else if (c == 2) { ph.z = vph; px.z = vpx; py.z = vpy; }
            else             { ph.w = vph; px.w = vpx; py.w = vpy; }
        }
        const int idx = kk * 256 + tid;
        out_phi[idx] = ph;
        out_px[idx]  = px;
        out_py[idx]  = py;
    }
}

extern "C" void kernel_launch(void* const* d_in, const int* in_sizes, int n_in,
                              void* d_out, int out_size, void* d_ws, size_t ws_size,
                              hipStream_t stream) {
    const float* x     = (const float*)d_in[0];   // [4096, 2]
    const float* nodes = (const float*)d_in[1];   // [4096, 2]
    float* out  = (float*)d_out;                  // 3 * 4096 * 4096 floats
    float* mind = (float*)d_ws;                   // [4096] nearest distances

    nearest_kernel<<<N_NODES, 256, 0, stream>>>(nodes, mind);
    rkpm_kernel<<<B_PTS, 256, 0, stream>>>(x, nodes, mind, out);
}